// Round 6
// baseline (120.007 us; speedup 1.0000x reference)
//
#include <hip/hip_runtime.h>
#include <math.h>

#define NP 65536
#define NJ 16
#define WID 64
#define HH 64
#define NPOU 4
#define NSUB 2
#define L2E2 2.8853900817779268f   // 2*log2(e)

typedef __attribute__((ext_vector_type(8))) short short8;
typedef __attribute__((ext_vector_type(4))) float f32x4;
typedef __attribute__((ext_vector_type(4))) int int4v;

// swizzled LDS layout: 64 bf16 per row (128 B = 8 chunks of 16 B), chunk ^= row&7
#define CHUNK_US(row, chunk) ((((row) << 6)) + ((((chunk) ^ ((row) & 7))) << 3))
__device__ __forceinline__ int usIdx(int row, int col) {
    return ((row) << 6) + ((((col >> 3) ^ (row & 7))) << 3) + (col & 7);
}

__device__ __forceinline__ unsigned short f2bf(float f) {   // RNE (weights, one-time)
    unsigned u = __float_as_uint(f);
    u += 0x7FFFu + ((u >> 16) & 1u);
    return (unsigned short)(u >> 16);
}
__device__ __forceinline__ unsigned short rhu(float f) {
    return (unsigned short)((__float_as_uint(f) + 0x8000u) >> 16);
}
__device__ __forceinline__ unsigned pk2(float a, float b) { // integer pack (pou kernel)
    unsigned ua = __float_as_uint(a) + 0x8000u;
    unsigned ub = __float_as_uint(b) + 0x8000u;
    return __builtin_amdgcn_perm(ub, ua, 0x07060302u);
}
__device__ __forceinline__ unsigned cvtpk(float a, float b) { // HW pack: a->low, b->high, RNE
    unsigned r;
    asm("v_cvt_pk_bf16_f32 %0, %1, %2" : "=v"(r) : "v"(a), "v"(b));
    return r;
}
__device__ __forceinline__ float bf2f(unsigned short s) {
    return __uint_as_float(((unsigned)s) << 16);
}
// tanh with argument pre-scaled by 2*log2e: tanh(z) = 1 - 2/(2^y+1), y = 2*log2e*z
__device__ __forceinline__ float tanh2(float y) {
    float e = __builtin_amdgcn_exp2f(y);
    return fmaf(-2.0f, __builtin_amdgcn_rcpf(e + 1.0f), 1.0f);
}
__device__ __forceinline__ short8 mk8(unsigned a, unsigned b, unsigned c, unsigned d) {
    int4v t; t.x = (int)a; t.y = (int)b; t.z = (int)c; t.w = (int)d;
    return __builtin_bit_cast(short8, t);
}

// ================= POU network via MFMA (unchanged from passing R3/R4/R5) =================
__global__ __launch_bounds__(256) void pou_mfma_kernel(
    const float* __restrict__ x,
    const float* __restrict__ W0, const float* __restrict__ b0,
    const float* __restrict__ Wh, const float* __restrict__ bh,
    const float* __restrict__ Wl, const float* __restrict__ bl,
    float* __restrict__ w_all)
{
    __shared__ unsigned short sA[4 * 64 * 64];
    __shared__ unsigned short sWhT[NPOU * 64 * 64];
    __shared__ unsigned short sWlT[16 * 64];
    __shared__ float sW0a[HH], sW0b[HH], sB0[HH];
    __shared__ float sbh[NPOU * HH];
    __shared__ float sbl[NJ];

    const int tid  = threadIdx.x;
    const int wave = tid >> 6;
    const int lane = tid & 63;
    const int r15  = lane & 15;
    const int g    = lane >> 4;

    for (int idx = tid; idx < NPOU * HH * HH; idx += 256) {
        int r = idx >> 12, k = (idx >> 6) & 63, n = idx & 63;
        sWhT[r * 4096 + usIdx(n, k)] = f2bf(Wh[idx]);
    }
    for (int idx = tid; idx < HH * NJ; idx += 256) {
        int k = idx >> 4, j = idx & 15;
        sWlT[usIdx(j, k)] = f2bf(Wl[idx]);
    }
    if (tid < HH) { sW0a[tid] = W0[tid]; sW0b[tid] = W0[HH + tid]; sB0[tid] = b0[tid]; }
    for (int i = tid; i < NPOU * HH; i += 256) sbh[i] = bh[i];
    if (tid < NJ) sbl[tid] = bl[tid];
    __syncthreads();

    unsigned short* myA = &sA[wave * 4096];
    const int pbase = blockIdx.x * 256;

    {
        const int p = pbase + tid;
        float2 xv = ((const float2*)x)[p];
        float v[HH];
#pragma unroll
        for (int c = 0; c < HH; ++c)
            v[c] = fmaxf(fmaf(xv.x, sW0a[c], fmaf(xv.y, sW0b[c], sB0[c])), 0.0f);
#pragma unroll
        for (int c = 0; c < 8; ++c) {
            int4v r;
            r.x = (int)pk2(v[8 * c + 0], v[8 * c + 1]);
            r.y = (int)pk2(v[8 * c + 2], v[8 * c + 3]);
            r.z = (int)pk2(v[8 * c + 4], v[8 * c + 5]);
            r.w = (int)pk2(v[8 * c + 6], v[8 * c + 7]);
            *(int4v*)&myA[CHUNK_US(lane, c)] = r;
        }
    }

    float trunk[4][4][4];
#pragma unroll
    for (int mt = 0; mt < 4; ++mt)
#pragma unroll
        for (int nt = 0; nt < 4; ++nt)
#pragma unroll
            for (int q = 0; q < 4; ++q)
                trunk[mt][nt][q] = bf2f(myA[usIdx(mt * 16 + g * 4 + q, nt * 16 + r15)]);

#pragma unroll 1
    for (int r = 0; r < NPOU; ++r) {
        const unsigned short* wt = &sWhT[r * 4096];
        short8 bfr[2][4];
#pragma unroll
        for (int kc = 0; kc < 2; ++kc)
#pragma unroll
            for (int nt = 0; nt < 4; ++nt)
                bfr[kc][nt] = *(const short8*)&wt[CHUNK_US(nt * 16 + r15, kc * 4 + g)];
        float bias[4];
#pragma unroll
        for (int nt = 0; nt < 4; ++nt) bias[nt] = sbh[r * HH + nt * 16 + r15];

#pragma unroll
        for (int mt = 0; mt < 4; ++mt) {
            short8 a0 = *(const short8*)&myA[CHUNK_US(mt * 16 + r15, g)];
            short8 a1 = *(const short8*)&myA[CHUNK_US(mt * 16 + r15, 4 + g)];
            f32x4 acc[4];
#pragma unroll
            for (int nt = 0; nt < 4; ++nt) {
                acc[nt] = (f32x4)(0.0f);
                acc[nt] = __builtin_amdgcn_mfma_f32_16x16x32_bf16(a0, bfr[0][nt], acc[nt], 0, 0, 0);
                acc[nt] = __builtin_amdgcn_mfma_f32_16x16x32_bf16(a1, bfr[1][nt], acc[nt], 0, 0, 0);
            }
#pragma unroll
            for (int nt = 0; nt < 4; ++nt)
#pragma unroll
                for (int q = 0; q < 4; ++q) {
                    float t = trunk[mt][nt][q] + fmaxf(acc[nt][q] + bias[nt], 0.0f);
                    trunk[mt][nt][q] = t;
                    myA[usIdx(mt * 16 + g * 4 + q, nt * 16 + r15)] = rhu(t);
                }
        }
    }

    short8 bw0 = *(const short8*)&sWlT[CHUNK_US(r15, g)];
    short8 bw1 = *(const short8*)&sWlT[CHUNK_US(r15, 4 + g)];
    float lg[4][4], mx[4][4];
#pragma unroll
    for (int mt = 0; mt < 4; ++mt) {
        short8 a0 = *(const short8*)&myA[CHUNK_US(mt * 16 + r15, g)];
        short8 a1 = *(const short8*)&myA[CHUNK_US(mt * 16 + r15, 4 + g)];
        f32x4 acc = (f32x4)(0.0f);
        acc = __builtin_amdgcn_mfma_f32_16x16x32_bf16(a0, bw0, acc, 0, 0, 0);
        acc = __builtin_amdgcn_mfma_f32_16x16x32_bf16(a1, bw1, acc, 0, 0, 0);
#pragma unroll
        for (int q = 0; q < 4; ++q) { lg[mt][q] = acc[q] + sbl[r15]; mx[mt][q] = lg[mt][q]; }
    }
#pragma unroll
    for (int mask = 1; mask < 16; mask <<= 1)
#pragma unroll
        for (int mt = 0; mt < 4; ++mt)
#pragma unroll
            for (int q = 0; q < 4; ++q) mx[mt][q] = fmaxf(mx[mt][q], __shfl_xor(mx[mt][q], mask));
    float ev[4][4], sm[4][4];
#pragma unroll
    for (int mt = 0; mt < 4; ++mt)
#pragma unroll
        for (int q = 0; q < 4; ++q) { ev[mt][q] = __expf(lg[mt][q] - mx[mt][q]); sm[mt][q] = ev[mt][q]; }
#pragma unroll
    for (int mask = 1; mask < 16; mask <<= 1)
#pragma unroll
        for (int mt = 0; mt < 4; ++mt)
#pragma unroll
            for (int q = 0; q < 4; ++q) sm[mt][q] += __shfl_xor(sm[mt][q], mask);
#pragma unroll
    for (int mt = 0; mt < 4; ++mt)
#pragma unroll
        for (int q = 0; q < 4; ++q) {
            const int p = pbase + wave * 64 + mt * 16 + g * 4 + q;
            w_all[r15 * NP + p] = ev[mt][q] * __builtin_amdgcn_rcpf(sm[mt][q]);
        }
}

// ======== Subnet j, transposed chain, one 256-pt tile per block (R4 grid),
// ======== conflict-free staging order from R5 (k fastest -> contiguous LDS rows) ========
__global__ __launch_bounds__(256) void subnet_mfma_kernel(
    const float* __restrict__ x,
    const float* __restrict__ gW0, const float* __restrict__ gb0,
    const float* __restrict__ gWh, const float* __restrict__ gbh,
    const float* __restrict__ gWl, const float* __restrict__ gbl,
    const float* __restrict__ w_all,
    float* __restrict__ upart)
{
    __shared__ __align__(16) unsigned short sWt[NSUB * 64 * 64]; // W^T [out][in] bf16 swz, *2*l2e
    __shared__ __align__(16) float sW0a[WID], sW0b[WID], sB0[WID];
    __shared__ __align__(16) float sbh[NSUB * WID];
    __shared__ __align__(16) float sWl[WID];
    __shared__ float sbl1v;

    const int tid  = threadIdx.x;
    const int j    = blockIdx.y;
    const int wave = tid >> 6;
    const int lane = tid & 63;
    const int c    = lane & 15;
    const int g    = lane >> 4;

    // ---- stage weights (k fastest per lane: LDS writes contiguous per row -> 0 conflicts;
    //      global side is a stride-256B gather, L2-resident after the first blocks) ----
    {
        const float* src = gWh + j * (NSUB * WID * WID);
        for (int idx = tid; idx < NSUB * WID * WID; idx += 256) {
            int L = idx >> 12, n = (idx >> 6) & 63, k = idx & 63;
            sWt[L * 4096 + usIdx(n, k)] = f2bf(L2E2 * src[L * 4096 + k * 64 + n]);
        }
        if (tid < WID) {
            float w0 = gW0[j * 2 * WID + tid], w1 = gW0[j * 2 * WID + WID + tid];
            sW0a[tid] = 2.0f * L2E2 * w0;
            sW0b[tid] = 2.0f * L2E2 * w1;
            sB0[tid]  = L2E2 * (gb0[j * WID + tid] - w0 - w1);
        }
        if (tid < NSUB * WID) sbh[tid] = L2E2 * gbh[j * NSUB * WID + tid];
        if (tid < WID) sWl[tid] = gWl[j * WID + tid];
        if (tid == 0) sbl1v = gbl[j];
    }
    __syncthreads();

    const int pb = blockIdx.x * 256 + wave * 64;

    // ---- L0 directly in B-frag layout: lane computes feats {kc*32+8g+e} x 4 points ----
    short8 bf[2][4];   // [kc][nt]: B-frag of H^T (k = feature, col = point)
    {
        float xs0[4], xs1[4];
#pragma unroll
        for (int nt = 0; nt < 4; ++nt) {
            float2 xv = ((const float2*)x)[pb + nt * 16 + c];
            xs0[nt] = xv.x; xs1[nt] = xv.y;
        }
        f32x4 wa[2][2], wb[2][2], bb[2][2];
#pragma unroll
        for (int kc = 0; kc < 2; ++kc)
#pragma unroll
            for (int hf = 0; hf < 2; ++hf) {
                wa[kc][hf] = *(const f32x4*)&sW0a[kc * 32 + 8 * g + 4 * hf];
                wb[kc][hf] = *(const f32x4*)&sW0b[kc * 32 + 8 * g + 4 * hf];
                bb[kc][hf] = *(const f32x4*)&sB0 [kc * 32 + 8 * g + 4 * hf];
            }
        unsigned t[2][4][4];
#pragma unroll
        for (int kc = 0; kc < 2; ++kc)
#pragma unroll
            for (int pr = 0; pr < 4; ++pr) {
                const int h0 = pr >> 1, e0 = (2 * pr) & 3, e1 = e0 + 1;
#pragma unroll
                for (int nt = 0; nt < 4; ++nt) {
                    float v0 = tanh2(fmaf(xs0[nt], wa[kc][h0][e0], fmaf(xs1[nt], wb[kc][h0][e0], bb[kc][h0][e0])));
                    float v1 = tanh2(fmaf(xs0[nt], wa[kc][h0][e1], fmaf(xs1[nt], wb[kc][h0][e1], bb[kc][h0][e1])));
                    t[kc][nt][pr] = cvtpk(v0, v1);
                }
            }
#pragma unroll
        for (int kc = 0; kc < 2; ++kc)
#pragma unroll
            for (int nt = 0; nt < 4; ++nt)
                bf[kc][nt] = mk8(t[kc][nt][0], t[kc][nt][1], t[kc][nt][2], t[kc][nt][3]);
    }

    float red[4];
#pragma unroll
    for (int nt = 0; nt < 4; ++nt) red[nt] = 0.0f;

    // ---- hidden layers: D[out][pt] = W^T (A-frag) * H^T (B-frag) ----
#pragma unroll
    for (int L = 0; L < NSUB; ++L) {
        const unsigned short* wt = &sWt[L * 4096];
        short8 aw[4][2];
#pragma unroll
        for (int mt = 0; mt < 4; ++mt)
#pragma unroll
            for (int kc = 0; kc < 2; ++kc)
                aw[mt][kc] = *(const short8*)&wt[CHUNK_US(mt * 16 + c, kc * 4 + g)];
        f32x4 bias[4];
#pragma unroll
        for (int mt = 0; mt < 4; ++mt)
            bias[mt] = *(const f32x4*)&sbh[L * 64 + mt * 16 + 4 * g];

#pragma unroll
        for (int nt = 0; nt < 4; ++nt) {
            f32x4 acc[4];
#pragma unroll
            for (int mt = 0; mt < 4; ++mt) acc[mt] = bias[mt];   // bias as C-init
#pragma unroll
            for (int mt = 0; mt < 4; ++mt) {
                acc[mt] = __builtin_amdgcn_mfma_f32_16x16x32_bf16(aw[mt][0], bf[0][nt], acc[mt], 0, 0, 0);
                acc[mt] = __builtin_amdgcn_mfma_f32_16x16x32_bf16(aw[mt][1], bf[1][nt], acc[mt], 0, 0, 0);
            }

            if (L < NSUB - 1) {
                float h[4][4];
#pragma unroll
                for (int mt = 0; mt < 4; ++mt)
#pragma unroll
                    for (int q = 0; q < 4; ++q) h[mt][q] = tanh2(acc[mt][q]);
                // in-register C-layout -> B-frag transform (overwrite bf[*][nt])
#pragma unroll
                for (int kn = 0; kn < 2; ++kn) {
                    unsigned A0 = cvtpk(h[2 * kn][0],     h[2 * kn][1]);
                    unsigned A1 = cvtpk(h[2 * kn][2],     h[2 * kn][3]);
                    unsigned B0 = cvtpk(h[2 * kn + 1][0], h[2 * kn + 1][1]);
                    unsigned B1 = cvtpk(h[2 * kn + 1][2], h[2 * kn + 1][3]);
                    asm("v_permlane32_swap_b32 %0, %1" : "+v"(A0), "+v"(B0));
                    asm("v_permlane16_swap_b32 %0, %1" : "+v"(A0), "+v"(B0));
                    asm("v_permlane32_swap_b32 %0, %1" : "+v"(A1), "+v"(B1));
                    asm("v_permlane16_swap_b32 %0, %1" : "+v"(A1), "+v"(B1));
                    bf[kn][nt] = mk8(A0, A1, B0, B1);
                }
            } else {
                // last hidden layer: tanh then dot with Wl rows held per lane
#pragma unroll
                for (int mt = 0; mt < 4; ++mt) {
                    f32x4 wlv = *(const f32x4*)&sWl[mt * 16 + 4 * g];
#pragma unroll
                    for (int q = 0; q < 4; ++q)
                        red[nt] = fmaf(tanh2(acc[mt][q]), wlv[q], red[nt]);
                }
            }
        }
    }

    // ---- reduce over g-lane groups ----
#pragma unroll
    for (int nt = 0; nt < 4; ++nt) {
        red[nt] += __shfl_xor(red[nt], 16);
        red[nt] += __shfl_xor(red[nt], 32);
    }
    float u = (g & 1) ? ((g & 2) ? red[3] : red[1]) : ((g & 2) ? red[2] : red[0]);
    u += sbl1v;

    const int p = pb + lane;
    upart[j * NP + p] = u * w_all[j * NP + p];
}

// ================= Reduce over j + Dirichlet ansatz (float4) =================
__global__ __launch_bounds__(256) void reduce_kernel(
    const float* __restrict__ x,
    const float* __restrict__ upart,
    float* __restrict__ out)
{
    const int p4 = blockIdx.x * 256 + threadIdx.x;
    f32x4 s = (f32x4)(0.0f);
#pragma unroll
    for (int j = 0; j < NJ; ++j) s += *(const f32x4*)&upart[j * NP + 4 * p4];
    f32x4 xa = ((const f32x4*)x)[2 * p4];
    f32x4 xb = ((const f32x4*)x)[2 * p4 + 1];
    f32x4 o;
    o.x = s.x * __builtin_amdgcn_sinf(xa.x * 0.5f) * __builtin_amdgcn_sinf(xa.y * 0.5f);
    o.y = s.y * __builtin_amdgcn_sinf(xa.z * 0.5f) * __builtin_amdgcn_sinf(xa.w * 0.5f);
    o.z = s.z * __builtin_amdgcn_sinf(xb.x * 0.5f) * __builtin_amdgcn_sinf(xb.y * 0.5f);
    o.w = s.w * __builtin_amdgcn_sinf(xb.z * 0.5f) * __builtin_amdgcn_sinf(xb.w * 0.5f);
    *(f32x4*)&out[4 * p4] = o;
}

extern "C" void kernel_launch(void* const* d_in, const int* in_sizes, int n_in,
                              void* d_out, int out_size, void* d_ws, size_t ws_size,
                              hipStream_t stream) {
    const float* x      = (const float*)d_in[0];
    const float* sub_W0 = (const float*)d_in[1];
    const float* sub_b0 = (const float*)d_in[2];
    const float* sub_Wh = (const float*)d_in[3];
    const float* sub_bh = (const float*)d_in[4];
    const float* sub_Wl = (const float*)d_in[5];
    const float* sub_bl = (const float*)d_in[6];
    const float* pou_W0 = (const float*)d_in[7];
    const float* pou_b0 = (const float*)d_in[8];
    const float* pou_Wh = (const float*)d_in[9];
    const float* pou_bh = (const float*)d_in[10];
    const float* pou_Wl = (const float*)d_in[11];
    const float* pou_bl = (const float*)d_in[12];

    float* w_all = (float*)d_ws;                   // [J][P] 4 MB
    float* upart = (float*)d_ws + (size_t)NJ * NP; // [J][P] 4 MB

    pou_mfma_kernel<<<NP / 256, 256, 0, stream>>>(x, pou_W0, pou_b0, pou_Wh, pou_bh,
                                                  pou_Wl, pou_bl, w_all);

    dim3 g2(NP / 256, NJ);
    subnet_mfma_kernel<<<g2, 256, 0, stream>>>(x, sub_W0, sub_b0, sub_Wh, sub_bh,
                                               sub_Wl, sub_bl, w_all, upart);

    reduce_kernel<<<NP / 1024, 256, 0, stream>>>(x, upart, (float*)d_out);
}

// Round 7
// 72.962 us; speedup vs baseline: 1.6448x; 1.6448x over previous
//
#include <hip/hip_runtime.h>
#include <math.h>

#define NP 65536
#define NJ 16
#define WID 64
#define HH 64
#define NPOU 4
#define NSUB 2
#define L2E2 2.8853900817779268f   // 2*log2(e)

typedef __attribute__((ext_vector_type(8))) short short8;
typedef __attribute__((ext_vector_type(4))) float f32x4;
typedef __attribute__((ext_vector_type(4))) int int4v;

// swizzled LDS layout (pou + fallback): 64 bf16/row, chunk ^= row&7
#define CHUNK_US(row, chunk) ((((row) << 6)) + ((((chunk) ^ ((row) & 7))) << 3))
__device__ __forceinline__ int usIdx(int row, int col) {
    return ((row) << 6) + ((((col >> 3) ^ (row & 7))) << 3) + (col & 7);
}

__device__ __forceinline__ unsigned short f2bf(float f) {   // RNE
    unsigned u = __float_as_uint(f);
    u += 0x7FFFu + ((u >> 16) & 1u);
    return (unsigned short)(u >> 16);
}
__device__ __forceinline__ unsigned short rhu(float f) {
    return (unsigned short)((__float_as_uint(f) + 0x8000u) >> 16);
}
__device__ __forceinline__ unsigned pk2(float a, float b) { // integer pack (pou kernel)
    unsigned ua = __float_as_uint(a) + 0x8000u;
    unsigned ub = __float_as_uint(b) + 0x8000u;
    return __builtin_amdgcn_perm(ub, ua, 0x07060302u);
}
__device__ __forceinline__ unsigned cvtpk(float a, float b) { // HW pack, RNE
    unsigned r;
    asm("v_cvt_pk_bf16_f32 %0, %1, %2" : "=v"(r) : "v"(a), "v"(b));
    return r;
}
__device__ __forceinline__ float bf2f(unsigned short s) {
    return __uint_as_float(((unsigned)s) << 16);
}
// tanh with argument pre-scaled by 2*log2e: tanh(z) = 1 - 2/(2^y+1)
__device__ __forceinline__ float tanh2(float y) {
    float e = __builtin_amdgcn_exp2f(y);
    return fmaf(-2.0f, __builtin_amdgcn_rcpf(e + 1.0f), 1.0f);
}
__device__ __forceinline__ short8 mk8(unsigned a, unsigned b, unsigned c, unsigned d) {
    int4v t; t.x = (int)a; t.y = (int)b; t.z = (int)c; t.w = (int)d;
    return __builtin_bit_cast(short8, t);
}

// ================= POU network via MFMA (unchanged, passing since R3) =================
__global__ __launch_bounds__(256) void pou_mfma_kernel(
    const float* __restrict__ x,
    const float* __restrict__ W0, const float* __restrict__ b0,
    const float* __restrict__ Wh, const float* __restrict__ bh,
    const float* __restrict__ Wl, const float* __restrict__ bl,
    float* __restrict__ w_all)
{
    __shared__ unsigned short sA[4 * 64 * 64];
    __shared__ unsigned short sWhT[NPOU * 64 * 64];
    __shared__ unsigned short sWlT[16 * 64];
    __shared__ float sW0a[HH], sW0b[HH], sB0[HH];
    __shared__ float sbh[NPOU * HH];
    __shared__ float sbl[NJ];

    const int tid  = threadIdx.x;
    const int wave = tid >> 6;
    const int lane = tid & 63;
    const int r15  = lane & 15;
    const int g    = lane >> 4;

    for (int idx = tid; idx < NPOU * HH * HH; idx += 256) {
        int r = idx >> 12, k = (idx >> 6) & 63, n = idx & 63;
        sWhT[r * 4096 + usIdx(n, k)] = f2bf(Wh[idx]);
    }
    for (int idx = tid; idx < HH * NJ; idx += 256) {
        int k = idx >> 4, j = idx & 15;
        sWlT[usIdx(j, k)] = f2bf(Wl[idx]);
    }
    if (tid < HH) { sW0a[tid] = W0[tid]; sW0b[tid] = W0[HH + tid]; sB0[tid] = b0[tid]; }
    for (int i = tid; i < NPOU * HH; i += 256) sbh[i] = bh[i];
    if (tid < NJ) sbl[tid] = bl[tid];
    __syncthreads();

    unsigned short* myA = &sA[wave * 4096];
    const int pbase = blockIdx.x * 256;

    {
        const int p = pbase + tid;
        float2 xv = ((const float2*)x)[p];
        float v[HH];
#pragma unroll
        for (int c = 0; c < HH; ++c)
            v[c] = fmaxf(fmaf(xv.x, sW0a[c], fmaf(xv.y, sW0b[c], sB0[c])), 0.0f);
#pragma unroll
        for (int c = 0; c < 8; ++c) {
            int4v r;
            r.x = (int)pk2(v[8 * c + 0], v[8 * c + 1]);
            r.y = (int)pk2(v[8 * c + 2], v[8 * c + 3]);
            r.z = (int)pk2(v[8 * c + 4], v[8 * c + 5]);
            r.w = (int)pk2(v[8 * c + 6], v[8 * c + 7]);
            *(int4v*)&myA[CHUNK_US(lane, c)] = r;
        }
    }

    float trunk[4][4][4];
#pragma unroll
    for (int mt = 0; mt < 4; ++mt)
#pragma unroll
        for (int nt = 0; nt < 4; ++nt)
#pragma unroll
            for (int q = 0; q < 4; ++q)
                trunk[mt][nt][q] = bf2f(myA[usIdx(mt * 16 + g * 4 + q, nt * 16 + r15)]);

#pragma unroll 1
    for (int r = 0; r < NPOU; ++r) {
        const unsigned short* wt = &sWhT[r * 4096];
        short8 bfr[2][4];
#pragma unroll
        for (int kc = 0; kc < 2; ++kc)
#pragma unroll
            for (int nt = 0; nt < 4; ++nt)
                bfr[kc][nt] = *(const short8*)&wt[CHUNK_US(nt * 16 + r15, kc * 4 + g)];
        float bias[4];
#pragma unroll
        for (int nt = 0; nt < 4; ++nt) bias[nt] = sbh[r * HH + nt * 16 + r15];

#pragma unroll
        for (int mt = 0; mt < 4; ++mt) {
            short8 a0 = *(const short8*)&myA[CHUNK_US(mt * 16 + r15, g)];
            short8 a1 = *(const short8*)&myA[CHUNK_US(mt * 16 + r15, 4 + g)];
            f32x4 acc[4];
#pragma unroll
            for (int nt = 0; nt < 4; ++nt) {
                acc[nt] = (f32x4)(0.0f);
                acc[nt] = __builtin_amdgcn_mfma_f32_16x16x32_bf16(a0, bfr[0][nt], acc[nt], 0, 0, 0);
                acc[nt] = __builtin_amdgcn_mfma_f32_16x16x32_bf16(a1, bfr[1][nt], acc[nt], 0, 0, 0);
            }
#pragma unroll
            for (int nt = 0; nt < 4; ++nt)
#pragma unroll
                for (int q = 0; q < 4; ++q) {
                    float t = trunk[mt][nt][q] + fmaxf(acc[nt][q] + bias[nt], 0.0f);
                    trunk[mt][nt][q] = t;
                    myA[usIdx(mt * 16 + g * 4 + q, nt * 16 + r15)] = rhu(t);
                }
        }
    }

    short8 bw0 = *(const short8*)&sWlT[CHUNK_US(r15, g)];
    short8 bw1 = *(const short8*)&sWlT[CHUNK_US(r15, 4 + g)];
    float lg[4][4], mx[4][4];
#pragma unroll
    for (int mt = 0; mt < 4; ++mt) {
        short8 a0 = *(const short8*)&myA[CHUNK_US(mt * 16 + r15, g)];
        short8 a1 = *(const short8*)&myA[CHUNK_US(mt * 16 + r15, 4 + g)];
        f32x4 acc = (f32x4)(0.0f);
        acc = __builtin_amdgcn_mfma_f32_16x16x32_bf16(a0, bw0, acc, 0, 0, 0);
        acc = __builtin_amdgcn_mfma_f32_16x16x32_bf16(a1, bw1, acc, 0, 0, 0);
#pragma unroll
        for (int q = 0; q < 4; ++q) { lg[mt][q] = acc[q] + sbl[r15]; mx[mt][q] = lg[mt][q]; }
    }
#pragma unroll
    for (int mask = 1; mask < 16; mask <<= 1)
#pragma unroll
        for (int mt = 0; mt < 4; ++mt)
#pragma unroll
            for (int q = 0; q < 4; ++q) mx[mt][q] = fmaxf(mx[mt][q], __shfl_xor(mx[mt][q], mask));
    float ev[4][4], sm[4][4];
#pragma unroll
    for (int mt = 0; mt < 4; ++mt)
#pragma unroll
        for (int q = 0; q < 4; ++q) { ev[mt][q] = __expf(lg[mt][q] - mx[mt][q]); sm[mt][q] = ev[mt][q]; }
#pragma unroll
    for (int mask = 1; mask < 16; mask <<= 1)
#pragma unroll
        for (int mt = 0; mt < 4; ++mt)
#pragma unroll
            for (int q = 0; q < 4; ++q) sm[mt][q] += __shfl_xor(sm[mt][q], mask);
#pragma unroll
    for (int mt = 0; mt < 4; ++mt)
#pragma unroll
        for (int q = 0; q < 4; ++q) {
            const int p = pbase + wave * 64 + mt * 16 + g * 4 + q;
            w_all[r15 * NP + p] = ev[mt][q] * __builtin_amdgcn_rcpf(sm[mt][q]);
        }
}

// ================= Prep: transpose+scale+bf16 subnet weights into A-frag order ============
// wfrag[j][f] (short8): f = ((L*4+mt)*2+kc)*64 + lane; value = W^T[mt*16+(lane&15)][kc*32+8*(lane>>4)+e]
// prm[j][512]: [0:64) 2*l2e*W0row0 | [64:128) 2*l2e*W0row1 | [128:192) l2e*(b0-w00-w01)
//              [192:320) l2e*bh | [320:384) Wl | [384] bl
__global__ __launch_bounds__(256) void prep_kernel(
    const float* __restrict__ gW0, const float* __restrict__ gb0,
    const float* __restrict__ gWh, const float* __restrict__ gbh,
    const float* __restrict__ gWl, const float* __restrict__ gbl,
    int4v* __restrict__ wfrag, float* __restrict__ prm)
{
    const int j   = blockIdx.y;
    const int tid = threadIdx.x;
    const int f   = blockIdx.x * 256 + tid;
    const int lane = f & 63, kc = (f >> 6) & 1, mt = (f >> 7) & 3, L = f >> 9;
    const int c = lane & 15, g = lane >> 4;
    const int n = mt * 16 + c;

    const float* src = gWh + j * (NSUB * WID * WID) + L * 4096;
    unsigned w[4];
#pragma unroll
    for (int e2 = 0; e2 < 4; ++e2) {
        int k = kc * 32 + 8 * g + 2 * e2;
        float v0 = L2E2 * src[k * 64 + n];
        float v1 = L2E2 * src[(k + 1) * 64 + n];
        w[e2] = (unsigned)f2bf(v0) | ((unsigned)f2bf(v1) << 16);
    }
    int4v r; r.x = (int)w[0]; r.y = (int)w[1]; r.z = (int)w[2]; r.w = (int)w[3];
    wfrag[j * 1024 + f] = r;

    if (blockIdx.x == 0) {
        float* pj = prm + j * 512;
        if (tid < WID) {
            float w0 = gW0[j * 2 * WID + tid], w1 = gW0[j * 2 * WID + WID + tid];
            pj[tid]       = 2.0f * L2E2 * w0;
            pj[64 + tid]  = 2.0f * L2E2 * w1;
            pj[128 + tid] = L2E2 * (gb0[j * WID + tid] - w0 - w1);
        }
        if (tid < NSUB * WID) pj[192 + tid] = L2E2 * gbh[j * NSUB * WID + tid];
        if (tid < WID) pj[320 + tid] = gWl[j * WID + tid];
        if (tid == 0) pj[384] = gbl[j];
    }
}

// ======== Subnet j: zero LDS, zero barriers; weights direct from prepped frags ========
__global__ __launch_bounds__(256, 4) void subnet_nolds_kernel(
    const float* __restrict__ x,
    const short8* __restrict__ wfrag,
    const float* __restrict__ prm,
    const float* __restrict__ w_all,
    float* __restrict__ upart)
{
    const int tid  = threadIdx.x;
    const int j    = blockIdx.y;
    const int wave = tid >> 6;
    const int lane = tid & 63;
    const int c    = lane & 15;
    const int g    = lane >> 4;

    const float*  pj = prm + j * 512;
    const short8* wf = wfrag + j * 1024;
    const int pb = blockIdx.x * 256 + wave * 64;

    // ---- L0 directly in B-frag layout ----
    short8 bf[2][4];
    {
        float xs0[4], xs1[4];
#pragma unroll
        for (int nt = 0; nt < 4; ++nt) {
            float2 xv = ((const float2*)x)[pb + nt * 16 + c];
            xs0[nt] = xv.x; xs1[nt] = xv.y;
        }
        f32x4 wa[2][2], wb[2][2], bb[2][2];
#pragma unroll
        for (int kc = 0; kc < 2; ++kc)
#pragma unroll
            for (int hf = 0; hf < 2; ++hf) {
                wa[kc][hf] = *(const f32x4*)&pj[      kc * 32 + 8 * g + 4 * hf];
                wb[kc][hf] = *(const f32x4*)&pj[ 64 + kc * 32 + 8 * g + 4 * hf];
                bb[kc][hf] = *(const f32x4*)&pj[128 + kc * 32 + 8 * g + 4 * hf];
            }
        unsigned t[2][4][4];
#pragma unroll
        for (int kc = 0; kc < 2; ++kc)
#pragma unroll
            for (int pr = 0; pr < 4; ++pr) {
                const int h0 = pr >> 1, e0 = (2 * pr) & 3, e1 = e0 + 1;
#pragma unroll
                for (int nt = 0; nt < 4; ++nt) {
                    float v0 = tanh2(fmaf(xs0[nt], wa[kc][h0][e0], fmaf(xs1[nt], wb[kc][h0][e0], bb[kc][h0][e0])));
                    float v1 = tanh2(fmaf(xs0[nt], wa[kc][h0][e1], fmaf(xs1[nt], wb[kc][h0][e1], bb[kc][h0][e1])));
                    t[kc][nt][pr] = cvtpk(v0, v1);
                }
            }
#pragma unroll
        for (int kc = 0; kc < 2; ++kc)
#pragma unroll
            for (int nt = 0; nt < 4; ++nt)
                bf[kc][nt] = mk8(t[kc][nt][0], t[kc][nt][1], t[kc][nt][2], t[kc][nt][3]);
    }

    float red[4];
#pragma unroll
    for (int nt = 0; nt < 4; ++nt) red[nt] = 0.0f;

    // ---- hidden layers: A-frags straight from global (L2-resident) ----
#pragma unroll
    for (int L = 0; L < NSUB; ++L) {
        short8 aw[4][2];
#pragma unroll
        for (int mt = 0; mt < 4; ++mt)
#pragma unroll
            for (int kc = 0; kc < 2; ++kc)
                aw[mt][kc] = wf[((L * 4 + mt) * 2 + kc) * 64 + lane];
        f32x4 bias[4];
#pragma unroll
        for (int mt = 0; mt < 4; ++mt)
            bias[mt] = *(const f32x4*)&pj[192 + L * 64 + mt * 16 + 4 * g];

#pragma unroll
        for (int nt = 0; nt < 4; ++nt) {
            f32x4 acc[4];
#pragma unroll
            for (int mt = 0; mt < 4; ++mt) acc[mt] = bias[mt];
#pragma unroll
            for (int mt = 0; mt < 4; ++mt) {
                acc[mt] = __builtin_amdgcn_mfma_f32_16x16x32_bf16(aw[mt][0], bf[0][nt], acc[mt], 0, 0, 0);
                acc[mt] = __builtin_amdgcn_mfma_f32_16x16x32_bf16(aw[mt][1], bf[1][nt], acc[mt], 0, 0, 0);
            }

            if (L < NSUB - 1) {
                float h[4][4];
#pragma unroll
                for (int mt = 0; mt < 4; ++mt)
#pragma unroll
                    for (int q = 0; q < 4; ++q) h[mt][q] = tanh2(acc[mt][q]);
#pragma unroll
                for (int kn = 0; kn < 2; ++kn) {
                    unsigned A0 = cvtpk(h[2 * kn][0],     h[2 * kn][1]);
                    unsigned A1 = cvtpk(h[2 * kn][2],     h[2 * kn][3]);
                    unsigned B0 = cvtpk(h[2 * kn + 1][0], h[2 * kn + 1][1]);
                    unsigned B1 = cvtpk(h[2 * kn + 1][2], h[2 * kn + 1][3]);
                    asm("v_permlane32_swap_b32 %0, %1" : "+v"(A0), "+v"(B0));
                    asm("v_permlane16_swap_b32 %0, %1" : "+v"(A0), "+v"(B0));
                    asm("v_permlane32_swap_b32 %0, %1" : "+v"(A1), "+v"(B1));
                    asm("v_permlane16_swap_b32 %0, %1" : "+v"(A1), "+v"(B1));
                    bf[kn][nt] = mk8(A0, A1, B0, B1);
                }
            } else {
#pragma unroll
                for (int mt = 0; mt < 4; ++mt) {
                    f32x4 wlv = *(const f32x4*)&pj[320 + mt * 16 + 4 * g];
#pragma unroll
                    for (int q = 0; q < 4; ++q)
                        red[nt] = fmaf(tanh2(acc[mt][q]), wlv[q], red[nt]);
                }
            }
        }
    }

#pragma unroll
    for (int nt = 0; nt < 4; ++nt) {
        red[nt] += __shfl_xor(red[nt], 16);
        red[nt] += __shfl_xor(red[nt], 32);
    }
    float u = (g & 1) ? ((g & 2) ? red[3] : red[1]) : ((g & 2) ? red[2] : red[0]);
    u += pj[384];

    const int p = pb + lane;
    upart[j * NP + p] = u * w_all[j * NP + p];
}

// ======== Fallback subnet (exact R4 structure, proven 77 us) if ws too small ========
__global__ __launch_bounds__(256) void subnet_mfma_fallback(
    const float* __restrict__ x,
    const float* __restrict__ gW0, const float* __restrict__ gb0,
    const float* __restrict__ gWh, const float* __restrict__ gbh,
    const float* __restrict__ gWl, const float* __restrict__ gbl,
    const float* __restrict__ w_all,
    float* __restrict__ upart)
{
    __shared__ __align__(16) unsigned short sWt[NSUB * 64 * 64];
    __shared__ __align__(16) float sW0a[WID], sW0b[WID], sB0[WID];
    __shared__ __align__(16) float sbh[NSUB * WID];
    __shared__ __align__(16) float sWl[WID];
    __shared__ float sbl1v;

    const int tid  = threadIdx.x;
    const int j    = blockIdx.y;
    const int wave = tid >> 6;
    const int lane = tid & 63;
    const int c    = lane & 15;
    const int g    = lane >> 4;

    {
        const float* src = gWh + j * (NSUB * WID * WID);
        for (int idx = tid; idx < NSUB * WID * WID; idx += 256) {
            int L = idx >> 12, rem = idx & 4095;
            int k = rem >> 6, n = rem & 63;
            sWt[L * 4096 + usIdx(n, k)] = f2bf(L2E2 * src[idx]);
        }
        if (tid < WID) {
            float w0 = gW0[j * 2 * WID + tid], w1 = gW0[j * 2 * WID + WID + tid];
            sW0a[tid] = 2.0f * L2E2 * w0;
            sW0b[tid] = 2.0f * L2E2 * w1;
            sB0[tid]  = L2E2 * (gb0[j * WID + tid] - w0 - w1);
        }
        if (tid < NSUB * WID) sbh[tid] = L2E2 * gbh[j * NSUB * WID + tid];
        if (tid < WID) sWl[tid] = gWl[j * WID + tid];
        if (tid == 0) sbl1v = gbl[j];
    }
    __syncthreads();

    const int pb = blockIdx.x * 256 + wave * 64;

    short8 bf[2][4];
    {
        float xs0[4], xs1[4];
#pragma unroll
        for (int nt = 0; nt < 4; ++nt) {
            float2 xv = ((const float2*)x)[pb + nt * 16 + c];
            xs0[nt] = xv.x; xs1[nt] = xv.y;
        }
        f32x4 wa[2][2], wb[2][2], bb[2][2];
#pragma unroll
        for (int kc = 0; kc < 2; ++kc)
#pragma unroll
            for (int hf = 0; hf < 2; ++hf) {
                wa[kc][hf] = *(const f32x4*)&sW0a[kc * 32 + 8 * g + 4 * hf];
                wb[kc][hf] = *(const f32x4*)&sW0b[kc * 32 + 8 * g + 4 * hf];
                bb[kc][hf] = *(const f32x4*)&sB0 [kc * 32 + 8 * g + 4 * hf];
            }
        unsigned t[2][4][4];
#pragma unroll
        for (int kc = 0; kc < 2; ++kc)
#pragma unroll
            for (int pr = 0; pr < 4; ++pr) {
                const int h0 = pr >> 1, e0 = (2 * pr) & 3, e1 = e0 + 1;
#pragma unroll
                for (int nt = 0; nt < 4; ++nt) {
                    float v0 = tanh2(fmaf(xs0[nt], wa[kc][h0][e0], fmaf(xs1[nt], wb[kc][h0][e0], bb[kc][h0][e0])));
                    float v1 = tanh2(fmaf(xs0[nt], wa[kc][h0][e1], fmaf(xs1[nt], wb[kc][h0][e1], bb[kc][h0][e1])));
                    t[kc][nt][pr] = cvtpk(v0, v1);
                }
            }
#pragma unroll
        for (int kc = 0; kc < 2; ++kc)
#pragma unroll
            for (int nt = 0; nt < 4; ++nt)
                bf[kc][nt] = mk8(t[kc][nt][0], t[kc][nt][1], t[kc][nt][2], t[kc][nt][3]);
    }

    float red[4];
#pragma unroll
    for (int nt = 0; nt < 4; ++nt) red[nt] = 0.0f;

#pragma unroll
    for (int L = 0; L < NSUB; ++L) {
        const unsigned short* wt = &sWt[L * 4096];
        short8 aw[4][2];
#pragma unroll
        for (int mt = 0; mt < 4; ++mt)
#pragma unroll
            for (int kc = 0; kc < 2; ++kc)
                aw[mt][kc] = *(const short8*)&wt[CHUNK_US(mt * 16 + c, kc * 4 + g)];
        f32x4 bias[4];
#pragma unroll
        for (int mt = 0; mt < 4; ++mt)
            bias[mt] = *(const f32x4*)&sbh[L * 64 + mt * 16 + 4 * g];

#pragma unroll
        for (int nt = 0; nt < 4; ++nt) {
            f32x4 acc[4];
#pragma unroll
            for (int mt = 0; mt < 4; ++mt) acc[mt] = bias[mt];
#pragma unroll
            for (int mt = 0; mt < 4; ++mt) {
                acc[mt] = __builtin_amdgcn_mfma_f32_16x16x32_bf16(aw[mt][0], bf[0][nt], acc[mt], 0, 0, 0);
                acc[mt] = __builtin_amdgcn_mfma_f32_16x16x32_bf16(aw[mt][1], bf[1][nt], acc[mt], 0, 0, 0);
            }

            if (L < NSUB - 1) {
                float h[4][4];
#pragma unroll
                for (int mt = 0; mt < 4; ++mt)
#pragma unroll
                    for (int q = 0; q < 4; ++q) h[mt][q] = tanh2(acc[mt][q]);
#pragma unroll
                for (int kn = 0; kn < 2; ++kn) {
                    unsigned A0 = cvtpk(h[2 * kn][0],     h[2 * kn][1]);
                    unsigned A1 = cvtpk(h[2 * kn][2],     h[2 * kn][3]);
                    unsigned B0 = cvtpk(h[2 * kn + 1][0], h[2 * kn + 1][1]);
                    unsigned B1 = cvtpk(h[2 * kn + 1][2], h[2 * kn + 1][3]);
                    asm("v_permlane32_swap_b32 %0, %1" : "+v"(A0), "+v"(B0));
                    asm("v_permlane16_swap_b32 %0, %1" : "+v"(A0), "+v"(B0));
                    asm("v_permlane32_swap_b32 %0, %1" : "+v"(A1), "+v"(B1));
                    asm("v_permlane16_swap_b32 %0, %1" : "+v"(A1), "+v"(B1));
                    bf[kn][nt] = mk8(A0, A1, B0, B1);
                }
            } else {
#pragma unroll
                for (int mt = 0; mt < 4; ++mt) {
                    f32x4 wlv = *(const f32x4*)&sWl[mt * 16 + 4 * g];
#pragma unroll
                    for (int q = 0; q < 4; ++q)
                        red[nt] = fmaf(tanh2(acc[mt][q]), wlv[q], red[nt]);
                }
            }
        }
    }

#pragma unroll
    for (int nt = 0; nt < 4; ++nt) {
        red[nt] += __shfl_xor(red[nt], 16);
        red[nt] += __shfl_xor(red[nt], 32);
    }
    float u = (g & 1) ? ((g & 2) ? red[3] : red[1]) : ((g & 2) ? red[2] : red[0]);
    u += sbl1v;

    const int p = pb + lane;
    upart[j * NP + p] = u * w_all[j * NP + p];
}

// ================= Reduce over j + Dirichlet ansatz (float4) =================
__global__ __launch_bounds__(256) void reduce_kernel(
    const float* __restrict__ x,
    const float* __restrict__ upart,
    float* __restrict__ out)
{
    const int p4 = blockIdx.x * 256 + threadIdx.x;
    f32x4 s = (f32x4)(0.0f);
#pragma unroll
    for (int j = 0; j < NJ; ++j) s += *(const f32x4*)&upart[j * NP + 4 * p4];
    f32x4 xa = ((const f32x4*)x)[2 * p4];
    f32x4 xb = ((const f32x4*)x)[2 * p4 + 1];
    f32x4 o;
    o.x = s.x * __builtin_amdgcn_sinf(xa.x * 0.5f) * __builtin_amdgcn_sinf(xa.y * 0.5f);
    o.y = s.y * __builtin_amdgcn_sinf(xa.z * 0.5f) * __builtin_amdgcn_sinf(xa.w * 0.5f);
    o.z = s.z * __builtin_amdgcn_sinf(xb.x * 0.5f) * __builtin_amdgcn_sinf(xb.y * 0.5f);
    o.w = s.w * __builtin_amdgcn_sinf(xb.z * 0.5f) * __builtin_amdgcn_sinf(xb.w * 0.5f);
    *(f32x4*)&out[4 * p4] = o;
}

extern "C" void kernel_launch(void* const* d_in, const int* in_sizes, int n_in,
                              void* d_out, int out_size, void* d_ws, size_t ws_size,
                              hipStream_t stream) {
    const float* x      = (const float*)d_in[0];
    const float* sub_W0 = (const float*)d_in[1];
    const float* sub_b0 = (const float*)d_in[2];
    const float* sub_Wh = (const float*)d_in[3];
    const float* sub_bh = (const float*)d_in[4];
    const float* sub_Wl = (const float*)d_in[5];
    const float* sub_bl = (const float*)d_in[6];
    const float* pou_W0 = (const float*)d_in[7];
    const float* pou_b0 = (const float*)d_in[8];
    const float* pou_Wh = (const float*)d_in[9];
    const float* pou_bh = (const float*)d_in[10];
    const float* pou_Wl = (const float*)d_in[11];
    const float* pou_bl = (const float*)d_in[12];

    float* w_all = (float*)d_ws;                   // [J][P] 4 MB
    float* upart = (float*)d_ws + (size_t)NJ * NP; // [J][P] 4 MB
    char*  extra = (char*)d_ws + (size_t)2 * NJ * NP * 4;
    void*  wfrag = (void*)extra;                           // 256 KB: [J][1024] short8
    float* prm   = (float*)(extra + (size_t)NJ * 1024 * 16); // 32 KB: [J][512]

    const size_t need = (size_t)2 * NJ * NP * 4 + (size_t)NJ * 1024 * 16 + (size_t)NJ * 512 * 4;
    const bool use_prep = (ws_size >= need);

    pou_mfma_kernel<<<NP / 256, 256, 0, stream>>>(x, pou_W0, pou_b0, pou_Wh, pou_bh,
                                                  pou_Wl, pou_bl, w_all);

    if (use_prep) {
        dim3 gp(4, NJ);
        prep_kernel<<<gp, 256, 0, stream>>>(sub_W0, sub_b0, sub_Wh, sub_bh, sub_Wl, sub_bl,
                                            (int4v*)wfrag, prm);
        dim3 g2(NP / 256, NJ);
        subnet_nolds_kernel<<<g2, 256, 0, stream>>>(x, (const short8*)wfrag, prm, w_all, upart);
    } else {
        dim3 g2(NP / 256, NJ);
        subnet_mfma_fallback<<<g2, 256, 0, stream>>>(x, sub_W0, sub_b0, sub_Wh, sub_bh,
                                                     sub_Wl, sub_bl, w_all, upart);
    }

    reduce_kernel<<<NP / 1024, 256, 0, stream>>>(x, upart, (float*)d_out);
}